// Round 4
// baseline (60.769 us; speedup 1.0000x reference)
//
#include <hip/hip_runtime.h>

// Problem constants (match reference setup_inputs)
#define NB 8
#define NM 64
#define NA 49104
#define NC 80
#define EPSF 1e-4f
#define NEGB 256   // neg blocks per image
#define ANCB 192   // anchor blocks per image (192*256 = 49152 >= 49104)

// Per-block partials; every slot written unconditionally -> no memset needed.
struct Ws {
    float negp[NB][NEGB];
    float corrp[NB][ANCB];
    float regp[NB][ANCB];
    float npp[NB][ANCB];
};

__device__ __forceinline__ float waveReduceSumF(float v) {
    #pragma unroll
    for (int off = 32; off > 0; off >>= 1) v += __shfl_down(v, off, 64);
    return v;
}

// Kernel 1: neg[j] = sum over all A*C of 0.75 * p^2 * (-log(1-p))
__global__ void neg_kernel(const float4* __restrict__ cls, Ws* __restrict__ ws) {
    const int j = blockIdx.y;
    const int per4 = NA * NC / 4;  // 982080
    const float4* base = cls + (size_t)j * per4;
    float s0 = 0.0f, s1 = 0.0f;
    const int stride = NEGB * 256;
    for (int i = blockIdx.x * 256 + threadIdx.x; i < per4; i += stride) {
        float4 v = base[i];
        float p0 = fminf(fmaxf(v.x, EPSF), 1.0f - EPSF);
        float p1 = fminf(fmaxf(v.y, EPSF), 1.0f - EPSF);
        float p2 = fminf(fmaxf(v.z, EPSF), 1.0f - EPSF);
        float p3 = fminf(fmaxf(v.w, EPSF), 1.0f - EPSF);
        s0 += p0 * p0 * (-__logf(1.0f - p0));
        s1 += p1 * p1 * (-__logf(1.0f - p1));
        s0 += p2 * p2 * (-__logf(1.0f - p2));
        s1 += p3 * p3 * (-__logf(1.0f - p3));
    }
    float s = 0.75f * (s0 + s1);
    __shared__ float sred[4];
    s = waveReduceSumF(s);
    const int wid = threadIdx.x >> 6;
    if ((threadIdx.x & 63) == 0) sred[wid] = s;
    __syncthreads();
    if (threadIdx.x == 0)
        ws->negp[j][blockIdx.x] = sred[0] + sred[1] + sred[2] + sred[3];
}

// Kernel 2: per-anchor IoU argmax over 64 boxes (division-free, fully
// unrolled -> batched LDS reads with immediate offsets), focal correction,
// smooth-L1 regression. One anchor per thread, all scalar state.
__global__ void anchor_kernel(const float* __restrict__ boxes,
                              const int* __restrict__ labels,
                              const float4* __restrict__ anchors4,
                              const float* __restrict__ cls,
                              const float4* __restrict__ reg,
                              Ws* __restrict__ ws) {
    const int j = blockIdx.y;
    __shared__ float4 sboxA[NM];   // x1,y1,x2,y2
    __shared__ float2 sboxB[NM];   // area, label(as float)
    if (threadIdx.x < NM) {
        const int m = threadIdx.x;
        float4 b = ((const float4*)boxes)[j * NM + m];
        sboxA[m] = b;
        sboxB[m] = make_float2((b.z - b.x) * (b.w - b.y),
                               (float)labels[j * NM + m]);
    }
    __syncthreads();

    const int a = blockIdx.x * 256 + threadIdx.x;
    const int ai = a < NA ? a : NA - 1;
    float4 an = anchors4[ai];          // (y1,x1,y2,x2)
    const float ay1 = an.x, ax1 = an.y, ay2 = an.z, ax2 = an.w;
    const float aare = (ay2 - ay1) * (ax2 - ax1);

    float besti = -2.0f, bestu = 1.0f;
    int bi = 0;
    #pragma unroll
    for (int m = 0; m < NM; ++m) {
        float4 b = sboxA[m];
        float2 e = sboxB[m];
        float iw = fminf(ax2, b.z) - fmaxf(ax1, b.x);
        float ih = fminf(ay2, b.w) - fmaxf(ay1, b.y);
        iw = fmaxf(iw, 0.0f);
        ih = fmaxf(ih, 0.0f);
        float inter = iw * ih;
        float ua = fmaxf(aare + e.x - inter, 1e-8f);
        // masked GT (label==0): iou = -1 exactly -> numer = -ua
        float numer = (e.y != 0.0f) ? inter : -ua;
        // iou_m > best  <=>  numer*bestu > besti*ua  (ua,bestu > 0)
        bool upd = numer * bestu > besti * ua;
        besti = upd ? numer : besti;
        bestu = upd ? ua : bestu;
        bi    = upd ? m : bi;
    }

    float corr = 0.0f, regl = 0.0f, npf = 0.0f;
    if (a < NA) {
        float4 bb = sboxA[bi];
        float2 ee = sboxB[bi];
        const bool big = ee.x > 100.0f;
        const float thr = big ? 0.5f : 0.15f;
        const bool pos = besti >= thr * bestu;
        if (pos) {
            npf = 1.0f;
            const int al = (int)ee.y - 1;   // label>=1 guaranteed when pos
            float p = cls[((size_t)j * NA + a) * NC + al];
            p = fminf(fmaxf(p, EPSF), 1.0f - EPSF);
            const float om = 1.0f - p;
            corr = 0.25f * om * om * (-__logf(p)) - 0.75f * p * p * (-__logf(om));

            const float aw = ax2 - ax1, ah = ay2 - ay1;
            const float acx = ax1 + 0.5f * aw, acy = ay1 + 0.5f * ah;
            float gw = bb.z - bb.x;
            float gh = bb.w - bb.y;
            const float gcx = bb.x + 0.5f * gw;
            const float gcy = bb.y + 0.5f * gh;
            gw = fmaxf(gw, 1.0f);
            gh = fmaxf(gh, 1.0f);
            float4 r = reg[(size_t)j * NA + a];
            const float t0 = (gcy - acy) / ah;
            const float t1 = (gcx - acx) / aw;
            const float t2 = __logf(gh / ah);
            const float t3 = __logf(gw / aw);
            const float d0 = fabsf(t0 - r.x);
            const float d1 = fabsf(t1 - r.y);
            const float d2 = fabsf(t2 - r.z);
            const float d3 = fabsf(t3 - r.w);
            const float ninth = 1.0f / 9.0f;
            const float c = 0.5f / 9.0f;
            regl  = (d0 <= ninth) ? 4.5f * d0 * d0 : d0 - c;
            regl += (d1 <= ninth) ? 4.5f * d1 * d1 : d1 - c;
            regl += (d2 <= ninth) ? 4.5f * d2 * d2 : d2 - c;
            regl += (d3 <= ninth) ? 4.5f * d3 * d3 : d3 - c;
        }
    }
    __shared__ float sred[3][4];
    corr = waveReduceSumF(corr);
    regl = waveReduceSumF(regl);
    npf  = waveReduceSumF(npf);
    const int wid = threadIdx.x >> 6;
    if ((threadIdx.x & 63) == 0) {
        sred[0][wid] = corr; sred[1][wid] = regl; sred[2][wid] = npf;
    }
    __syncthreads();
    if (threadIdx.x == 0) {
        ws->corrp[j][blockIdx.x] = sred[0][0] + sred[0][1] + sred[0][2] + sred[0][3];
        ws->regp[j][blockIdx.x]  = sred[1][0] + sred[1][1] + sred[1][2] + sred[1][3];
        ws->npp[j][blockIdx.x]   = sred[2][0] + sred[2][1] + sred[2][2] + sred[2][3];
    }
}

// Kernel 3: 8 waves, wave j reduces image j's partials; thread 0 emits output.
__global__ void finalize_kernel(const Ws* __restrict__ ws, float* __restrict__ out) {
    __shared__ float scls[NB], sreg[NB];
    const int w = threadIdx.x >> 6;     // image
    const int lane = threadIdx.x & 63;
    float ns = 0.0f, cs = 0.0f, rs = 0.0f, np = 0.0f;
    #pragma unroll
    for (int i = lane; i < NEGB; i += 64) ns += ws->negp[w][i];
    #pragma unroll
    for (int i = lane; i < ANCB; i += 64) {
        cs += ws->corrp[w][i];
        rs += ws->regp[w][i];
        np += ws->npp[w][i];
    }
    ns = waveReduceSumF(ns);
    cs = waveReduceSumF(cs);
    rs = waveReduceSumF(rs);
    np = waveReduceSumF(np);
    if (lane == 0) {
        float d = fmaxf(np, 1.0f);
        scls[w] = (ns + cs) / d;
        sreg[w] = (np > 0.0f) ? rs / (4.0f * d) : 0.0f;
    }
    __syncthreads();
    if (threadIdx.x == 0) {
        float acc = 0.0f, b = 0.0f;
        #pragma unroll
        for (int jj = 0; jj < NB; ++jj) { acc += scls[jj]; b += sreg[jj]; }
        out[0] = acc / (float)NB;
        out[1] = (b / (float)NB) * 50.0f;
    }
}

extern "C" void kernel_launch(void* const* d_in, const int* in_sizes, int n_in,
                              void* d_out, int out_size, void* d_ws, size_t ws_size,
                              hipStream_t stream) {
    const float* boxes   = (const float*)d_in[0];
    const int*   labels  = (const int*)d_in[1];
    const float* anchors = (const float*)d_in[2];
    const float* cls     = (const float*)d_in[3];
    const float* reg     = (const float*)d_in[4];
    float* out = (float*)d_out;
    Ws* ws = (Ws*)d_ws;

    dim3 gN(NEGB, NB);
    neg_kernel<<<gN, 256, 0, stream>>>((const float4*)cls, ws);

    dim3 gA(ANCB, NB);
    anchor_kernel<<<gA, 256, 0, stream>>>(boxes, labels, (const float4*)anchors,
                                          cls, (const float4*)reg, ws);

    finalize_kernel<<<1, 512, 0, stream>>>(ws, out);
}

// Round 5
// 43.707 us; speedup vs baseline: 1.3904x; 1.3904x over previous
//
#include <hip/hip_runtime.h>

// Problem constants (match reference setup_inputs)
#define NB 8
#define NM 64
#define NA 49104
#define NC 80
#define EPSF 1e-4f
#define NEGB 192   // neg-role blocks per image
#define ANCB 192   // anchor-role blocks per image (192*256 = 49152 >= 49104)
#define BIG9 1e9f

// d_ws layout. clean[j][m] = {x1,y1,x2,y2,area,labelf,pad,pad} (32B records).
// All partial slots written unconditionally every launch -> no memset needed.
struct Ws {
    float clean[NB][NM][8];     // 16 KB, 32B-aligned records
    float negp[NB][NEGB];
    float corrp[NB][ANCB];
    float regp[NB][ANCB];
    float npp[NB][ANCB];
};

__device__ __forceinline__ float waveReduceSumF(float v) {
    #pragma unroll
    for (int off = 32; off > 0; off >>= 1) v += __shfl_down(v, off, 64);
    return v;
}

// Kernel 0: build clean per-image box records.
// Masked (label==0) boxes get coords=1e9 => iw/ih clamp to 0 => inter=0,
// ua=aare>0 => iou=0. Ties at iou<=0.15 never produce pos, so this is
// loss-equivalent to the reference's iou=-1 masking.
__global__ void setup_kernel(const float4* __restrict__ boxes4,
                             const int* __restrict__ labels,
                             Ws* __restrict__ ws) {
    const int t = threadIdx.x;          // 0..511
    const int j = t >> 6, m = t & 63;
    float4 b = boxes4[t];
    const int lab = labels[t];
    const bool valid = lab != 0;
    const float x1 = valid ? b.x : BIG9;
    const float y1 = valid ? b.y : BIG9;
    const float x2 = valid ? b.z : BIG9;
    const float y2 = valid ? b.w : BIG9;
    ws->clean[j][m][0] = x1;
    ws->clean[j][m][1] = y1;
    ws->clean[j][m][2] = x2;
    ws->clean[j][m][3] = y2;
    ws->clean[j][m][4] = (x2 - x1) * (y2 - y1);   // 0 for masked
    ws->clean[j][m][5] = (float)lab;
    ws->clean[j][m][6] = 0.0f;
    ws->clean[j][m][7] = 0.0f;
}

// Kernel 1 (fused): blockIdx.x < NEGB -> neg role; else anchor role.
__global__ void main_kernel(const float4* __restrict__ cls4,
                            const float* __restrict__ cls,
                            const float4* __restrict__ anchors4,
                            const float4* __restrict__ reg,
                            const float* __restrict__ clean,  // == ws->clean
                            Ws* __restrict__ ws) {
    const int j = blockIdx.y;
    __shared__ float sred[3][4];

    if (blockIdx.x < NEGB) {
        // ---- neg role: sum 0.75*p^2*(-log(1-p)), 1-deep prefetch pipeline ----
        const int per4 = NA * NC / 4;  // 982080
        const float4* base = cls4 + (size_t)j * per4;
        const int stride = NEGB * 256;
        int i = blockIdx.x * 256 + threadIdx.x;
        float s0 = 0.0f, s1 = 0.0f;
        if (i < per4) {
            float4 v = base[i];
            for (;;) {
                const int inext = i + stride;
                const bool more = inext < per4;
                float4 vn;
                if (more) vn = base[inext];
                float p0 = fminf(fmaxf(v.x, EPSF), 1.0f - EPSF);
                float p1 = fminf(fmaxf(v.y, EPSF), 1.0f - EPSF);
                float p2 = fminf(fmaxf(v.z, EPSF), 1.0f - EPSF);
                float p3 = fminf(fmaxf(v.w, EPSF), 1.0f - EPSF);
                s0 += p0 * p0 * (-__logf(1.0f - p0));
                s1 += p1 * p1 * (-__logf(1.0f - p1));
                s0 += p2 * p2 * (-__logf(1.0f - p2));
                s1 += p3 * p3 * (-__logf(1.0f - p3));
                if (!more) break;
                v = vn; i = inext;
            }
        }
        float s = 0.75f * (s0 + s1);
        s = waveReduceSumF(s);
        const int wid = threadIdx.x >> 6;
        if ((threadIdx.x & 63) == 0) sred[0][wid] = s;
        __syncthreads();
        if (threadIdx.x == 0)
            ws->negp[j][blockIdx.x] = sred[0][0] + sred[0][1] + sred[0][2] + sred[0][3];
    } else {
        // ---- anchor role: SGPR-resident boxes, memory-op-free 64-box loop ----
        const int bx = blockIdx.x - NEGB;
        const int a = bx * 256 + threadIdx.x;
        const int ai = a < NA ? a : NA - 1;
        float4 an = anchors4[ai];          // (y1,x1,y2,x2)
        const float ay1 = an.x, ax1 = an.y, ay2 = an.z, ax2 = an.w;
        const float aare = (ay2 - ay1) * (ax2 - ax1);

        // Uniform base address (j is uniform) + constant offsets -> s_load.
        const float* cb = clean + (size_t)j * NM * 8;

        float besti = -2.0f, bestu = 1.0f;
        int bi = 0;
        #pragma unroll
        for (int m = 0; m < NM; ++m) {
            const float bx1 = cb[m * 8 + 0];
            const float by1 = cb[m * 8 + 1];
            const float bx2 = cb[m * 8 + 2];
            const float by2 = cb[m * 8 + 3];
            const float bar = cb[m * 8 + 4];
            float iw = fmaxf(fminf(ax2, bx2) - fmaxf(ax1, bx1), 0.0f);
            float ih = fmaxf(fminf(ay2, by2) - fmaxf(ay1, by1), 0.0f);
            float inter = iw * ih;
            float ua = fmaxf(aare + bar - inter, 1e-8f);
            // iou_m > best  <=>  inter*bestu > besti*ua  (ua,bestu > 0)
            bool upd = inter * bestu > besti * ua;
            besti = upd ? inter : besti;
            bestu = upd ? ua : bestu;
            bi    = upd ? m : bi;
        }

        float corr = 0.0f, regl = 0.0f, npf = 0.0f;
        if (a < NA) {
            const float* bb = cb + bi * 8;        // per-lane gather, L2-hot
            const float bbx1 = bb[0], bby1 = bb[1], bbx2 = bb[2], bby2 = bb[3];
            const float bar = bb[4], labf = bb[5];
            const bool big = bar > 100.0f;
            const float thr = big ? 0.5f : 0.15f;
            const bool pos = besti >= thr * bestu;
            if (pos) {
                npf = 1.0f;
                const int al = (int)labf - 1;     // label>=1 guaranteed when pos
                float p = cls[((size_t)j * NA + a) * NC + al];
                p = fminf(fmaxf(p, EPSF), 1.0f - EPSF);
                const float om = 1.0f - p;
                corr = 0.25f * om * om * (-__logf(p)) - 0.75f * p * p * (-__logf(om));

                const float aw = ax2 - ax1, ah = ay2 - ay1;
                const float acx = ax1 + 0.5f * aw, acy = ay1 + 0.5f * ah;
                float gw = bbx2 - bbx1;
                float gh = bby2 - bby1;
                const float gcx = bbx1 + 0.5f * gw;
                const float gcy = bby1 + 0.5f * gh;
                gw = fmaxf(gw, 1.0f);
                gh = fmaxf(gh, 1.0f);
                float4 r = reg[(size_t)j * NA + a];
                const float t0 = (gcy - acy) / ah;
                const float t1 = (gcx - acx) / aw;
                const float t2 = __logf(gh / ah);
                const float t3 = __logf(gw / aw);
                const float d0 = fabsf(t0 - r.x);
                const float d1 = fabsf(t1 - r.y);
                const float d2 = fabsf(t2 - r.z);
                const float d3 = fabsf(t3 - r.w);
                const float ninth = 1.0f / 9.0f;
                const float c = 0.5f / 9.0f;
                regl  = (d0 <= ninth) ? 4.5f * d0 * d0 : d0 - c;
                regl += (d1 <= ninth) ? 4.5f * d1 * d1 : d1 - c;
                regl += (d2 <= ninth) ? 4.5f * d2 * d2 : d2 - c;
                regl += (d3 <= ninth) ? 4.5f * d3 * d3 : d3 - c;
            }
        }
        corr = waveReduceSumF(corr);
        regl = waveReduceSumF(regl);
        npf  = waveReduceSumF(npf);
        const int wid = threadIdx.x >> 6;
        if ((threadIdx.x & 63) == 0) {
            sred[0][wid] = corr; sred[1][wid] = regl; sred[2][wid] = npf;
        }
        __syncthreads();
        if (threadIdx.x == 0) {
            ws->corrp[j][bx] = sred[0][0] + sred[0][1] + sred[0][2] + sred[0][3];
            ws->regp[j][bx]  = sred[1][0] + sred[1][1] + sred[1][2] + sred[1][3];
            ws->npp[j][bx]   = sred[2][0] + sred[2][1] + sred[2][2] + sred[2][3];
        }
    }
}

// Kernel 2: 8 waves, wave j reduces image j's partials; thread 0 emits output.
__global__ void finalize_kernel(const Ws* __restrict__ ws, float* __restrict__ out) {
    __shared__ float scls[NB], sreg[NB];
    const int w = threadIdx.x >> 6;     // image
    const int lane = threadIdx.x & 63;
    float ns = 0.0f, cs = 0.0f, rs = 0.0f, np = 0.0f;
    #pragma unroll
    for (int i = lane; i < NEGB; i += 64) ns += ws->negp[w][i];
    #pragma unroll
    for (int i = lane; i < ANCB; i += 64) {
        cs += ws->corrp[w][i];
        rs += ws->regp[w][i];
        np += ws->npp[w][i];
    }
    ns = waveReduceSumF(ns);
    cs = waveReduceSumF(cs);
    rs = waveReduceSumF(rs);
    np = waveReduceSumF(np);
    if (lane == 0) {
        float d = fmaxf(np, 1.0f);
        scls[w] = (ns + cs) / d;
        sreg[w] = (np > 0.0f) ? rs / (4.0f * d) : 0.0f;
    }
    __syncthreads();
    if (threadIdx.x == 0) {
        float acc = 0.0f, b = 0.0f;
        #pragma unroll
        for (int jj = 0; jj < NB; ++jj) { acc += scls[jj]; b += sreg[jj]; }
        out[0] = acc / (float)NB;
        out[1] = (b / (float)NB) * 50.0f;
    }
}

extern "C" void kernel_launch(void* const* d_in, const int* in_sizes, int n_in,
                              void* d_out, int out_size, void* d_ws, size_t ws_size,
                              hipStream_t stream) {
    const float* boxes   = (const float*)d_in[0];
    const int*   labels  = (const int*)d_in[1];
    const float* anchors = (const float*)d_in[2];
    const float* cls     = (const float*)d_in[3];
    const float* reg     = (const float*)d_in[4];
    float* out = (float*)d_out;
    Ws* ws = (Ws*)d_ws;

    setup_kernel<<<1, NB * NM, 0, stream>>>((const float4*)boxes, labels, ws);

    dim3 g(NEGB + ANCB, NB);
    main_kernel<<<g, 256, 0, stream>>>((const float4*)cls, cls,
                                       (const float4*)anchors, (const float4*)reg,
                                       (const float*)&ws->clean[0][0][0], ws);

    finalize_kernel<<<1, 512, 0, stream>>>(ws, out);
}